// Round 7
// baseline (4005.663 us; speedup 1.0000x reference)
//
#include <hip/hip_runtime.h>
#include <stdint.h>

// ---------------------------------------------------------------------------
// EMMPTNet: 2-layer bidir LSTM (T=2048,H=128) -> self-attn (attn matrix is
// output 1) -> 2-hop GCN (50k nodes, 600k edges) -> MLP (output 0).
// fp32 I/O. LSTM recurrence now uses MFMA (v_mfma_f32_16x16x32_f16):
// per direction one 256-thread block (4 waves, 1/EU); wave w owns outputs
// {32w..32w+32} x 4 gates as 8 N-tiles x 4 chained K-MFMAs. A-operand = h
// replicated over M (rows equal => every lane's D.x is the gate sum for
// col=lane&15). Weights live as B-frags (128 regs) read natively by MFMA
// (kills round-5/6's v_accvgpr_read tax). Tail split by row-group parity.
// GCN via CSR gather (no fp32 atomics), hidden under the recurrences.
// ---------------------------------------------------------------------------

#define T_SEQ 2048
#define NNODE 50000
#define NEDGE 600000

typedef _Float16 half8 __attribute__((ext_vector_type(8)));
typedef float float4v __attribute__((ext_vector_type(4)));

static __device__ __forceinline__ float fast_rcp(float x) {
#if __has_builtin(__builtin_amdgcn_rcpf)
    return __builtin_amdgcn_rcpf(x);
#else
    return 1.f / x;
#endif
}
static __device__ __forceinline__ float exp2_fast(float x) {
#if __has_builtin(__builtin_amdgcn_exp2f)
    return __builtin_amdgcn_exp2f(x);
#else
    return exp2f(x);
#endif
}

// gate pre-scales for exp2-based activations:
// sigmoid(x) = rcp(1 + 2^(-1.4427 x));  tanh(x) = 1 - 2 rcp(1 + 2^(2.8854 x))
#define SIG_SCALE  (-1.44269504f)
#define TANH_SCALE ( 2.88539008f)

// ---------------- workspace layout (4-byte word offsets) ----------------
constexpr size_t OFF_XGT   = 0;                      // [1024][2048] xg transposed (pre-scaled)
constexpr size_t OFF_HT0   = OFF_XGT + 2097152;      // [256][2048] h0 transposed
constexpr size_t OFF_HT1   = OFF_HT0 + 524288;       // [256][2048] h1 transposed
constexpr size_t OFF_Q     = OFF_HT1 + 524288;       // [2048][128]
constexpr size_t OFF_K     = OFF_Q + 262144;
constexpr size_t OFF_V     = OFF_K + 262144;
constexpr size_t OFF_AROW  = OFF_V + 262144;         // [2048]
constexpr size_t OFF_AV    = OFF_AROW + 2048;        // [128]
constexpr size_t OFF_FEATS = OFF_AV + 128;           // [1152]
constexpr size_t OFF_F1    = OFF_FEATS + 1152;       // [576]
constexpr size_t OFF_F2    = OFF_F1 + 576;           // [256]
constexpr size_t OFF_GSUM  = OFF_F2 + 256;           // [128]   (memset group start)
constexpr size_t OFF_OUTW  = OFF_GSUM + 128;         // [50000] fp32
constexpr size_t OFF_DEG   = OFF_OUTW + 50000;       // [50000] int (memset group end)
constexpr size_t OFF_ROWP  = OFF_DEG + 50000;        // [50000] int
constexpr size_t OFF_CUR   = OFF_ROWP + 50000;       // [50000] int
constexpr size_t OFF_WPK   = OFF_CUR + 50000;        // [131072] u32 B-frag fp16 w_hh (pre-scaled)
constexpr size_t OFF_EPACK = OFF_WPK + 131072;       // [600000] uint2
constexpr size_t WS_WORDS  = OFF_EPACK + 1200000;

// ---------------- one-time prep: pack w_hh into MFMA B-fragment order.
// u32 index bits: jp(0-1) L(2-7) kc(8-9) t(10-12) w(13-14) d(15) layer(16).
// tile t: gate m = t&3, col-group cg = t>>2.
// B[k][n]: n = L&15 -> row = d*512 + m*128 + 32w + 16cg + (L&15)
//          k = (L>>4)*8 + j -> col = kc*32 + (L>>4)*8 + 2jp(+1)
__global__ __launch_bounds__(256) void prep_kernel(
    const float* __restrict__ w_hh0, const float* __restrict__ w_hh1,
    uint32_t* __restrict__ wpk)
{
    int i = blockIdx.x * 256 + threadIdx.x;
    if (i >= 131072) return;
    int jp = i & 3;
    int L  = (i >> 2) & 63;
    int kc = (i >> 8) & 3;
    int t  = (i >> 10) & 7;
    int w  = (i >> 13) & 3;
    int d  = (i >> 15) & 1;
    int layer = i >> 16;
    int m = t & 3, cg = t >> 2;
    const float* W = layer ? w_hh1 : w_hh0;
    int row = d * 512 + m * 128 + 32 * w + 16 * cg + (L & 15);
    int col = kc * 32 + (L >> 4) * 8 + 2 * jp;
    float sc = (m == 2) ? TANH_SCALE : SIG_SCALE;
    _Float16 h2[2];
    h2[0] = (_Float16)(W[(size_t)row * 128 + col] * sc);
    h2[1] = (_Float16)(W[(size_t)row * 128 + col + 1] * sc);
    uint32_t u;
    __builtin_memcpy(&u, h2, 4);
    wpk[i] = u;
}

// ---------------- layer-0 input projection -> xgT[row][t] (biases folded,
// rows pre-scaled by gate constants)
__global__ __launch_bounds__(512) void xg0_kernel(
    const float* __restrict__ g_mol, const float* __restrict__ w_ih,
    const float* __restrict__ b_ih, const float* __restrict__ b_hh,
    float* __restrict__ xgT)
{
    int b = blockIdx.x;
    int dir = b >> 7, t0 = (b & 127) * 16;
    int r = threadIdx.x;
    __shared__ float xs[272];
    if (r < 272) xs[r] = g_mol[t0 * 17 + r];
    __syncthreads();
    const float* wrow = w_ih + (size_t)(dir * 512 + r) * 17;
    float wv[17];
#pragma unroll
    for (int k = 0; k < 17; ++k) wv[k] = wrow[k];
    float bias = b_ih[dir * 512 + r] + b_hh[dir * 512 + r];
    float rs = ((r >> 7) == 2) ? TANH_SCALE : SIG_SCALE;
    float acc[16];
#pragma unroll
    for (int tt = 0; tt < 16; ++tt) {
        float a = bias;
#pragma unroll
        for (int k = 0; k < 17; ++k) a += xs[tt * 17 + k] * wv[k];
        acc[tt] = a * rs;
    }
    float* orow = xgT + (size_t)(dir * 512 + r) * 2048 + t0;
    *(float4*)(orow + 0)  = make_float4(acc[0], acc[1], acc[2], acc[3]);
    *(float4*)(orow + 4)  = make_float4(acc[4], acc[5], acc[6], acc[7]);
    *(float4*)(orow + 8)  = make_float4(acc[8], acc[9], acc[10], acc[11]);
    *(float4*)(orow + 12) = make_float4(acc[12], acc[13], acc[14], acc[15]);
}

// ---------------- layer-1 input projection: hT0 -> xgT[row][t] (pre-scaled)
__global__ __launch_bounds__(512) void xg1_kernel(
    const float* __restrict__ hT0, const float* __restrict__ w_ih,
    const float* __restrict__ b_ih, const float* __restrict__ b_hh,
    float* __restrict__ xgT)
{
    int b = blockIdx.x;
    int dir = b >> 7, t0 = (b & 127) * 16;
    int tid = threadIdx.x;
    __shared__ float xs[16 * 256];            // [tt][k]
    for (int u = tid; u < 1024; u += 512) {
        int k = u >> 2, j4 = u & 3;
        float4 v = *(const float4*)(hT0 + (size_t)k * 2048 + t0 + 4 * j4);
        xs[(4 * j4 + 0) * 256 + k] = v.x;
        xs[(4 * j4 + 1) * 256 + k] = v.y;
        xs[(4 * j4 + 2) * 256 + k] = v.z;
        xs[(4 * j4 + 3) * 256 + k] = v.w;
    }
    __syncthreads();
    int r = tid;
    float bias = b_ih[dir * 512 + r] + b_hh[dir * 512 + r];
    float rs = ((r >> 7) == 2) ? TANH_SCALE : SIG_SCALE;
    float acc[16];
#pragma unroll
    for (int tt = 0; tt < 16; ++tt) acc[tt] = bias;
    const float4* w4 = reinterpret_cast<const float4*>(w_ih + (size_t)(dir * 512 + r) * 256);
    const float4* xs4 = reinterpret_cast<const float4*>(xs);
    for (int k4 = 0; k4 < 64; ++k4) {
        float4 w = w4[k4];
#pragma unroll
        for (int tt = 0; tt < 16; ++tt) {
            float4 x = xs4[tt * 64 + k4];
            acc[tt] += x.x * w.x + x.y * w.y + x.z * w.z + x.w * w.w;
        }
    }
    float* orow = xgT + (size_t)(dir * 512 + r) * 2048 + t0;
    *(float4*)(orow + 0)  = make_float4(acc[0] * rs, acc[1] * rs, acc[2] * rs, acc[3] * rs);
    *(float4*)(orow + 4)  = make_float4(acc[4] * rs, acc[5] * rs, acc[6] * rs, acc[7] * rs);
    *(float4*)(orow + 8)  = make_float4(acc[8] * rs, acc[9] * rs, acc[10] * rs, acc[11] * rs);
    *(float4*)(orow + 12) = make_float4(acc[12] * rs, acc[13] * rs, acc[14] * rs, acc[15] * rs);
}

// ---------------- fused: blocks 0,1 = MFMA LSTM recurrence (one per dir);
// blocks 2..255 = side work (mode 0: edge hist + outw; mode 1: CSR gather).
// 84KB LDS -> exactly 1 block/CU; 256 thr = 4 waves = 1 wave/EU.
__global__ __launch_bounds__(256) __attribute__((amdgpu_waves_per_eu(1, 1)))
void lstm_fused_kernel(
    const float* __restrict__ xgT, const uint32_t* __restrict__ wpk,
    float* __restrict__ hT, int mode,
    const int* __restrict__ esrc, const int* __restrict__ edst,
    const float* __restrict__ ew,
    int* __restrict__ deg, float* __restrict__ outw,
    const int* __restrict__ rowp, const uint2* __restrict__ epack,
    const float* __restrict__ feat_seq,
    const float* __restrict__ Wgc1, const float* __restrict__ bgc1,
    float* __restrict__ gsum)
{
    __shared__ __align__(16) float smem[21504];   // 84 KB: forces 1 block/CU
    const int tid = threadIdx.x;

    if (blockIdx.x >= 2) {
        if (mode == 0) {
            int stride = (gridDim.x - 2) * 256;
            for (int e = (blockIdx.x - 2) * 256 + tid; e < NEDGE; e += stride) {
                atomicAdd(&deg[edst[e]], 1);
                atomicAdd(&outw[esrc[e]], ew[e]);
            }
        } else {
            // CSR gather: agg1 row -> relu(agg1@W+b) -> gsum += outw[n]*h1
            float* wt   = smem;            // 16384 = W_gc1 [k][o]
            float* bg   = smem + 16384;    // 128
            float* aggl = smem + 16512;    // 4 waves x 128
            float* gbuf = smem + 17536;    // 128
            {
                float4* d4 = (float4*)wt;
                const float4* s4 = (const float4*)Wgc1;
                for (int u = tid; u < 4096; u += 256) d4[u] = s4[u];
                if (tid < 128) { bg[tid] = bgc1[tid]; gbuf[tid] = 0.f; }
            }
            __syncthreads();
            int wv = tid >> 6, lane = tid & 63;
            float ga0 = 0.f, ga1 = 0.f;
            int nwaves = (gridDim.x - 2) * 4;
            for (int n = (blockIdx.x - 2) * 4 + wv; n < NNODE; n += nwaves) {
                int st = rowp[n];
                int dg = deg[n];
                float a0 = 0.f, a1 = 0.f;
                for (int i = 0; i < dg; ++i) {
                    uint2 ep = epack[st + i];
                    float w = __uint_as_float(ep.y);
                    float2 f = *(const float2*)(feat_seq + (size_t)ep.x * 128 + 2 * lane);
                    a0 += w * f.x;
                    a1 += w * f.y;
                }
                *(float2*)&aggl[wv * 128 + 2 * lane] = make_float2(a0, a1);
                float h0 = bg[2 * lane], h1v = bg[2 * lane + 1];
                for (int k = 0; k < 128; ++k) {
                    float av_ = aggl[wv * 128 + k];
                    float2 wv2 = *(const float2*)&wt[k * 128 + 2 * lane];
                    h0 += av_ * wv2.x;
                    h1v += av_ * wv2.y;
                }
                float ow = outw[n];
                ga0 += ow * fmaxf(h0, 0.f);
                ga1 += ow * fmaxf(h1v, 0.f);
            }
            atomicAdd(&gbuf[2 * lane], ga0);
            atomicAdd(&gbuf[2 * lane + 1], ga1);
            __syncthreads();
            if (tid < 128) atomicAdd(&gsum[tid], gbuf[tid]);
        }
        return;
    }

    // ---------------- MFMA LSTM recurrence ----------------
#if __has_builtin(__builtin_amdgcn_s_setprio)
    __builtin_amdgcn_s_setprio(3);
#endif
    const int dir = blockIdx.x;
    const int w   = tid >> 6;          // wave 0..3
    const int L   = tid & 63;
    const int rg  = L >> 4;            // row-group (M-replicated => redundant)
    const bool hi = (rg & 1);          // tail handles o1 vs o0
    const int o0  = 32 * w + (L & 15);
    const int osel = hi ? (o0 + 16) : o0;

    _Float16* hbuf = reinterpret_cast<_Float16*>(smem);   // [2][128] halfs

    // B-frags: 8 tiles x 4 kc, 16B each, lane-strided (stays in regs; MFMA
    // reads them natively, no accvgpr copies)
    const half8* wsrc = reinterpret_cast<const half8*>(wpk) + ((size_t)(dir * 4 + w) * 32) * 64;
    half8 bw[8][4];
#pragma unroll
    for (int t = 0; t < 8; ++t)
#pragma unroll
        for (int kc = 0; kc < 4; ++kc)
            bw[t][kc] = wsrc[(t * 4 + kc) * 64 + L];

    if (tid < 128) reinterpret_cast<uint32_t*>(hbuf)[tid] = 0u;  // both buffers
    float c = 0.f;
    __syncthreads();

    const float* xgb = xgT + (size_t)(dir * 512 + osel) * 2048;
    float* hrow = hT + (size_t)(dir * 128 + osel) * 2048;
    const bool dost = (L < 32);

    const int tt0 = dir ? 2047 : 0;
    float xc0 = xgb[tt0];
    float xc1 = xgb[tt0 + 262144];
    float xc2 = xgb[tt0 + 524288];
    float xc3 = xgb[tt0 + 786432];

    const float4v zro = {0.f, 0.f, 0.f, 0.f};

    for (int i = 0; i < 2048; ++i) {
        const int p = i & 1;
        const int tt = dir ? (2047 - i) : i;
        const int inx = (i + 1 < 2048) ? (i + 1) : i;
        const int tn = dir ? (2047 - inx) : inx;

        // A-frags: h chunk kc, k = kc*32 + rg*8 + j (matches B pack's k-map)
        const char* hbase = reinterpret_cast<const char*>(hbuf) + p * 256 + rg * 16;
        half8 Af[4];
#pragma unroll
        for (int kc = 0; kc < 4; ++kc)
            Af[kc] = *reinterpret_cast<const half8*>(hbase + kc * 64);

        float4v ac[8];
#pragma unroll
        for (int t = 0; t < 8; ++t)
            ac[t] = __builtin_amdgcn_mfma_f32_16x16x32_f16(Af[0], bw[t][0], zro, 0, 0, 0);
#pragma unroll
        for (int kc = 1; kc < 4; ++kc)
#pragma unroll
            for (int t = 0; t < 8; ++t)
                ac[t] = __builtin_amdgcn_mfma_f32_16x16x32_f16(Af[kc], bw[t][kc], ac[t], 0, 0, 0);

        // prefetch next step's xg (independent of MFMA results)
        float xn0 = xgb[tn];
        float xn1 = xgb[tn + 262144];
        float xn2 = xgb[tn + 524288];
        float xn3 = xgb[tn + 786432];

        // rows of D all equal (A M-replicated) => .x is the gate sum for this col
        float g0 = (hi ? ac[4].x : ac[0].x) + xc0;   // i
        float g1 = (hi ? ac[5].x : ac[1].x) + xc1;   // f
        float g2 = (hi ? ac[6].x : ac[2].x) + xc2;   // g (tanh)
        float g3 = (hi ? ac[7].x : ac[3].x) + xc3;   // o
        float iv = fast_rcp(1.f + exp2_fast(g0));
        float fv = fast_rcp(1.f + exp2_fast(g1));
        float gv = fmaf(-2.f, fast_rcp(1.f + exp2_fast(g2)), 1.f);
        float ov = fast_rcp(1.f + exp2_fast(g3));
        c = fmaf(fv, c, iv * gv);
        float th = fmaf(-2.f, fast_rcp(1.f + exp2_fast(TANH_SCALE * c)), 1.f);
        float hv = ov * th;

        hbuf[(p ^ 1) * 128 + osel] = (_Float16)hv;   // rg2/3 dup-write same value
        if (dost) hrow[tt] = hv;
        __syncthreads();
        xc0 = xn0; xc1 = xn1; xc2 = xn2; xc3 = xn3;
    }
}

// ---------------- CSR scan: deg -> rowp (exclusive), cursor copy
__global__ __launch_bounds__(1024) void scan_kernel(
    const int* __restrict__ deg, int* __restrict__ rowp, int* __restrict__ cur)
{
    __shared__ int part[1024];
    int t = threadIdx.x;
    int lo = t * 49, hi = min(lo + 49, NNODE);
    int s = 0;
    for (int i = lo; i < hi; ++i) s += deg[i];
    part[t] = s;
    __syncthreads();
    for (int off = 1; off < 1024; off <<= 1) {
        int v = (t >= off) ? part[t - off] : 0;
        __syncthreads();
        part[t] += v;
        __syncthreads();
    }
    int run = t ? part[t - 1] : 0;
    for (int i = lo; i < hi; ++i) {
        rowp[i] = run;
        cur[i] = run;
        run += deg[i];
    }
}

// ---------------- CSR fill: epack[pos] = {src, weight}
__global__ __launch_bounds__(512) void fill_kernel(
    const int* __restrict__ esrc, const int* __restrict__ edst,
    const float* __restrict__ ew, int* __restrict__ cur,
    uint2* __restrict__ epack)
{
    int e = blockIdx.x * 512 + threadIdx.x;
    if (e >= NEDGE) return;
    int d = edst[e];
    int pos = atomicAdd(&cur[d], 1);
    epack[pos] = make_uint2((unsigned)esrc[e], __float_as_uint(ew[e]));
}

// ---------------- q/k/v projection from hT1, 16 timesteps per block
__global__ __launch_bounds__(384) void qkv_kernel(
    const float* __restrict__ hT1,
    const float* __restrict__ Wq, const float* __restrict__ bq,
    const float* __restrict__ Wk, const float* __restrict__ bk,
    const float* __restrict__ Wv, const float* __restrict__ bv,
    float* __restrict__ q, float* __restrict__ k, float* __restrict__ v)
{
    int t0 = blockIdx.x * 16, tid = threadIdx.x;
    __shared__ float xs[16 * 256];
    for (int u = tid; u < 1024; u += 384) {
        int kk = u >> 2, j4 = u & 3;
        float4 vv = *(const float4*)(hT1 + (size_t)kk * 2048 + t0 + 4 * j4);
        xs[(4 * j4 + 0) * 256 + kk] = vv.x;
        xs[(4 * j4 + 1) * 256 + kk] = vv.y;
        xs[(4 * j4 + 2) * 256 + kk] = vv.z;
        xs[(4 * j4 + 3) * 256 + kk] = vv.w;
    }
    __syncthreads();
    int which = tid >> 7, j = tid & 127;
    const float* W = (which == 0) ? Wq : (which == 1) ? Wk : Wv;
    const float* B = (which == 0) ? bq : (which == 1) ? bk : bv;
    float* out = (which == 0) ? q : (which == 1) ? k : v;
    float bias = B[j];
    float acc[16];
#pragma unroll
    for (int tt = 0; tt < 16; ++tt) acc[tt] = bias;
    const float4* w4 = reinterpret_cast<const float4*>(W + (size_t)j * 256);
    const float4* xs4 = reinterpret_cast<const float4*>(xs);
    for (int k4 = 0; k4 < 64; ++k4) {
        float4 w = w4[k4];
#pragma unroll
        for (int tt = 0; tt < 16; ++tt) {
            float4 x = xs4[tt * 64 + k4];
            acc[tt] += x.x * w.x + x.y * w.y + x.z * w.z + x.w * w.w;
        }
    }
#pragma unroll
    for (int tt = 0; tt < 16; ++tt) out[(size_t)(t0 + tt) * 128 + j] = acc[tt];
}

// ---------------- scores = q @ k.T / sqrt(128), straight into d_out+1
__global__ __launch_bounds__(256) void scores_kernel(
    const float* __restrict__ q, const float* __restrict__ kmat, float* __restrict__ attn)
{
    int bi = blockIdx.y, bj = blockIdx.x, tid = threadIdx.x;
    __shared__ float qs[16][132];
    __shared__ float ks[16][132];
    for (int u = tid; u < 2048; u += 256) {
        int rr = u >> 7, cc = u & 127;
        qs[rr][cc] = q[(size_t)(bi * 16 + rr) * 128 + cc];
        ks[rr][cc] = kmat[(size_t)(bj * 16 + rr) * 128 + cc];
    }
    __syncthreads();
    int ty = tid >> 4, tx = tid & 15;
    const float4* qrow = reinterpret_cast<const float4*>(&qs[ty][0]);
    const float4* krow = reinterpret_cast<const float4*>(&ks[tx][0]);
    float acc = 0.f;
#pragma unroll
    for (int c4 = 0; c4 < 32; ++c4) {
        float4 a = qrow[c4], b = krow[c4];
        acc += a.x * b.x + a.y * b.y + a.z * b.z + a.w * b.w;
    }
    attn[(size_t)(bi * 16 + ty) * 2048 + (bj * 16 + tx)] = acc * 0.08838834764831845f;
}

// ---------------- softmax per row, in place; saves row 2047
__global__ __launch_bounds__(256) void softmax_kernel(
    float* __restrict__ attn, float* __restrict__ attnrow)
{
    int i = blockIdx.x, tid = threadIdx.x;
    float* row = attn + (size_t)i * 2048;
    __shared__ float red[256];
    float m = -1e30f;
    for (int j = tid; j < 2048; j += 256) m = fmaxf(m, row[j]);
    red[tid] = m; __syncthreads();
    for (int s = 128; s > 0; s >>= 1) { if (tid < s) red[tid] = fmaxf(red[tid], red[tid + s]); __syncthreads(); }
    m = red[0]; __syncthreads();
    float sum = 0.f;
    for (int j = tid; j < 2048; j += 256) sum += __expf(row[j] - m);
    red[tid] = sum; __syncthreads();
    for (int s = 128; s > 0; s >>= 1) { if (tid < s) red[tid] += red[tid + s]; __syncthreads(); }
    float inv = 1.f / red[0];
    for (int j = tid; j < 2048; j += 256) {
        float w = __expf(row[j] - m) * inv;
        row[j] = w;
        if (i == 2047) attnrow[j] = w;
    }
}

// ---------------- av[j] = sum_t attnrow[t] * v[t][j]
__global__ __launch_bounds__(128) void av_kernel(
    const float* __restrict__ attnrow, const float* __restrict__ v, float* __restrict__ av)
{
    int j = threadIdx.x;
    float acc = 0.f;
#pragma unroll 8
    for (int t = 0; t < 2048; ++t) acc += attnrow[t] * v[(size_t)t * 128 + j];
    av[j] = acc;
}

// ---------------- gmol = av @ Wfc.T + bfc -> feats[256..511]
__global__ __launch_bounds__(256) void gmolfc_kernel(
    const float* __restrict__ av, const float* __restrict__ Wfc, const float* __restrict__ bfc,
    float* __restrict__ feats)
{
    int o = threadIdx.x;
    __shared__ float a[128];
    if (o < 128) a[o] = av[o];
    __syncthreads();
    const float4* w4 = reinterpret_cast<const float4*>(Wfc + (size_t)o * 128);
    const float4* a4 = reinterpret_cast<const float4*>(a);
    float acc = bfc[o];
#pragma unroll 8
    for (int kk = 0; kk < 32; ++kk) {
        float4 w = w4[kk], x = a4[kk];
        acc += x.x * w.x + x.y * w.y + x.z * w.z + x.w * w.w;
    }
    feats[256 + o] = acc;
}

// ---------------- feats: hg (=(gsum/N)@W_gc2+b_gc2) + smiles + kmer
__global__ __launch_bounds__(256) void feats_kernel(
    const float* __restrict__ gsum, const float* __restrict__ W_gc2, const float* __restrict__ b_gc2,
    const float* __restrict__ smiles, const float* __restrict__ kmer, float* __restrict__ feats)
{
    int i = blockIdx.x * 256 + threadIdx.x;
    if (i < 256) {
        float dotv = 0.f;
#pragma unroll 4
        for (int k = 0; k < 128; ++k) dotv += gsum[k] * W_gc2[(size_t)k * 256 + i];
        feats[i] = b_gc2[i] + dotv * (1.f / (float)NNODE);
    } else if (i >= 512 && i < 1086) {
        feats[i] = smiles[i - 512];
    } else if (i >= 1086 && i < 1150) {
        feats[i] = kmer[i - 1086];
    }
}

// ---------------- MLP layers
__global__ __launch_bounds__(256) void mlp1_kernel(
    const float* __restrict__ feats, const float* __restrict__ W1, const float* __restrict__ b1,
    float* __restrict__ f1)
{
    int o = blockIdx.x, tid = threadIdx.x;
    const float* w = W1 + (size_t)o * 1150;
    float acc = 0.f;
    for (int k = tid; k < 1150; k += 256) acc += feats[k] * w[k];
    __shared__ float red[256];
    red[tid] = acc; __syncthreads();
    for (int s = 128; s > 0; s >>= 1) { if (tid < s) red[tid] += red[tid + s]; __syncthreads(); }
    if (tid == 0) f1[o] = fmaxf(red[0] + b1[o], 0.f);
}

__global__ __launch_bounds__(256) void mlp2_kernel(
    const float* __restrict__ f1, const float* __restrict__ W2, const float* __restrict__ b2,
    float* __restrict__ f2)
{
    int o = blockIdx.x, tid = threadIdx.x;
    const float* w = W2 + (size_t)o * 575;
    float acc = 0.f;
    for (int k = tid; k < 575; k += 256) acc += f1[k] * w[k];
    __shared__ float red[256];
    red[tid] = acc; __syncthreads();
    for (int s = 128; s > 0; s >>= 1) { if (tid < s) red[tid] += red[tid + s]; __syncthreads(); }
    if (tid == 0) f2[o] = fmaxf(red[0] + b2[o], 0.f);
}

__global__ __launch_bounds__(256) void mlp_tail_kernel(
    const float* __restrict__ f2,
    const float* __restrict__ W3, const float* __restrict__ b3,
    const float* __restrict__ W4, const float* __restrict__ b4,
    float* __restrict__ out)
{
    __shared__ float f2s[256];
    __shared__ float f3[64];
    int tid = threadIdx.x;
    f2s[tid] = f2[tid];
    __syncthreads();
    if (tid < 64) {
        const float* w = W3 + (size_t)tid * 256;
        float acc = b3[tid];
        for (int k = 0; k < 256; ++k) acc += f2s[k] * w[k];
        f3[tid] = fmaxf(acc, 0.f);
    }
    __syncthreads();
    if (tid == 0) {
        float acc = b4[0];
        for (int k = 0; k < 64; ++k) acc += f3[k] * W4[k];
        out[0] = acc;
    }
}

// ---------------------------------------------------------------------------
extern "C" void kernel_launch(void* const* d_in, const int* in_sizes, int n_in,
                              void* d_out, int out_size, void* d_ws, size_t ws_size,
                              hipStream_t stream)
{
    const float* g_mol   = (const float*)d_in[0];
    const float* feat_seq= (const float*)d_in[1];
    const float* smiles  = (const float*)d_in[2];
    const float* kmer    = (const float*)d_in[3];
    const float* edge_w  = (const float*)d_in[4];
    const float* w_ih0   = (const float*)d_in[5];
    const float* w_hh0   = (const float*)d_in[6];
    const float* b_ih0   = (const float*)d_in[7];
    const float* b_hh0   = (const float*)d_in[8];
    const float* w_ih1   = (const float*)d_in[9];
    const float* w_hh1   = (const float*)d_in[10];
    const float* b_ih1   = (const float*)d_in[11];
    const float* b_hh1   = (const float*)d_in[12];
    const float* Wq      = (const float*)d_in[13];
    const float* bq      = (const float*)d_in[14];
    const float* Wk      = (const float*)d_in[15];
    const float* bk      = (const float*)d_in[16];
    const float* Wv      = (const float*)d_in[17];
    const float* bv      = (const float*)d_in[18];
    const float* Wfc     = (const float*)d_in[19];
    const float* bfc     = (const float*)d_in[20];
    const float* W_gc1   = (const float*)d_in[21];
    const float* b_gc1   = (const float*)d_in[22];
    const float* W_gc2   = (const float*)d_in[23];
    const float* b_gc2   = (const float*)d_in[24];
    const float* W1      = (const float*)d_in[25];
    const float* b1      = (const float*)d_in[26];
    const float* W2      = (const float*)d_in[27];
    const float* b2      = (const float*)d_in[28];
    const float* W3      = (const float*)d_in[29];
    const float* b3      = (const float*)d_in[30];
    const float* W4      = (const float*)d_in[31];
    const float* b4      = (const float*)d_in[32];
    const int* esrc      = (const int*)d_in[33];
    const int* edst      = (const int*)d_in[34];

    float* ws    = (float*)d_ws;
    float* xgT   = ws + OFF_XGT;
    float* hT0   = ws + OFF_HT0;
    float* hT1   = ws + OFF_HT1;
    float* q     = ws + OFF_Q;
    float* k     = ws + OFF_K;
    float* v     = ws + OFF_V;
    float* arow  = ws + OFF_AROW;
    float* av    = ws + OFF_AV;
    float* feats = ws + OFF_FEATS;
    float* f1    = ws + OFF_F1;
    float* f2    = ws + OFF_F2;
    float* gsum  = ws + OFF_GSUM;
    float* outw  = ws + OFF_OUTW;
    int*   deg   = (int*)(ws + OFF_DEG);
    int*   rowp  = (int*)(ws + OFF_ROWP);
    int*   cur   = (int*)(ws + OFF_CUR);
    uint32_t* wpk = (uint32_t*)(ws + OFF_WPK);
    uint2* epack = (uint2*)(ws + OFF_EPACK);

    float* out_f = (float*)d_out;
    float* attn  = out_f + 1;   // [2048][2048] scores then softmax in place

    // zero gsum + outw + deg (contiguous)
    hipMemsetAsync(gsum, 0, (size_t)(128 + 50000 + 50000) * sizeof(float), stream);

    // weight prep + layer-0 input projection
    prep_kernel<<<512, 256, 0, stream>>>(w_hh0, w_hh1, wpk);
    xg0_kernel<<<256, 512, 0, stream>>>(g_mol, w_ih0, b_ih0, b_hh0, xgT);

    // layer-0 recurrence, edge histogram hidden under it (grid=256: 1 block/CU)
    lstm_fused_kernel<<<256, 256, 0, stream>>>(
        xgT, wpk, hT0, 0, esrc, edst, edge_w, deg, outw,
        rowp, epack, feat_seq, W_gc1, b_gc1, gsum);

    // CSR build
    scan_kernel<<<1, 1024, 0, stream>>>(deg, rowp, cur);
    fill_kernel<<<1172, 512, 0, stream>>>(esrc, edst, edge_w, cur, epack);

    // layer-1 input projection, then recurrence with GNN gather hidden under it
    xg1_kernel<<<256, 512, 0, stream>>>(hT0, w_ih1, b_ih1, b_hh1, xgT);
    lstm_fused_kernel<<<256, 256, 0, stream>>>(
        xgT, wpk + 65536, hT1, 1, esrc, edst, edge_w, deg, outw,
        rowp, epack, feat_seq, W_gc1, b_gc1, gsum);

    // attention
    qkv_kernel<<<128, 384, 0, stream>>>(hT1, Wq, bq, Wk, bk, Wv, bv, q, k, v);
    scores_kernel<<<dim3(128, 128), 256, 0, stream>>>(q, k, attn);
    softmax_kernel<<<2048, 256, 0, stream>>>(attn, arow);
    av_kernel<<<1, 128, 0, stream>>>(arow, v, av);
    gmolfc_kernel<<<1, 256, 0, stream>>>(av, Wfc, bfc, feats);
    feats_kernel<<<5, 256, 0, stream>>>(gsum, W_gc2, b_gc2, smiles, kmer, feats);

    // head
    mlp1_kernel<<<575, 256, 0, stream>>>(feats, W1, b1, f1);
    mlp2_kernel<<<256, 256, 0, stream>>>(f1, W2, b2, f2);
    mlp_tail_kernel<<<1, 256, 0, stream>>>(f2, W3, b3, W4, b4, out_f);
}

// Round 8
// 2514.381 us; speedup vs baseline: 1.5931x; 1.5931x over previous
//
#include <hip/hip_runtime.h>
#include <stdint.h>

// ---------------------------------------------------------------------------
// EMMPTNet: 2-layer bidir LSTM (T=2048,H=128) -> self-attn (attn matrix is
// output 1) -> 2-hop GCN (50k nodes, 600k edges) -> MLP (output 0).
// fp32 I/O. LSTM recurrence: MFMA (v_mfma_f32_16x16x32_f16), waves 0-3 of a
// 512-thread block; ALL global traffic hoisted out of the per-step barrier
// loop (round-7 lesson: every __syncthreads drains vmcnt(0), so per-step
// global loads/stores serialize L2/L3 latency into the recurrence). xg is
// staged per 16-step tile into LDS; h batched in regs, stored once per tile.
// Waves 4-7 idle during steps (barrier-matched) but give the CSR-gather side
// blocks 8 waves. GCN via CSR gather (no fp32 atomics).
// ---------------------------------------------------------------------------

#define T_SEQ 2048
#define NNODE 50000
#define NEDGE 600000

typedef _Float16 half8 __attribute__((ext_vector_type(8)));
typedef float float4v __attribute__((ext_vector_type(4)));

static __device__ __forceinline__ float fast_rcp(float x) {
#if __has_builtin(__builtin_amdgcn_rcpf)
    return __builtin_amdgcn_rcpf(x);
#else
    return 1.f / x;
#endif
}
static __device__ __forceinline__ float exp2_fast(float x) {
#if __has_builtin(__builtin_amdgcn_exp2f)
    return __builtin_amdgcn_exp2f(x);
#else
    return exp2f(x);
#endif
}

// gate pre-scales for exp2-based activations:
// sigmoid(x) = rcp(1 + 2^(-1.4427 x));  tanh(x) = 1 - 2 rcp(1 + 2^(2.8854 x))
#define SIG_SCALE  (-1.44269504f)
#define TANH_SCALE ( 2.88539008f)

// ---------------- workspace layout (4-byte word offsets) ----------------
constexpr size_t OFF_XGT   = 0;                      // [1024][2048] xg transposed (pre-scaled)
constexpr size_t OFF_HT0   = OFF_XGT + 2097152;      // [256][2048] h0 transposed
constexpr size_t OFF_HT1   = OFF_HT0 + 524288;       // [256][2048] h1 transposed
constexpr size_t OFF_Q     = OFF_HT1 + 524288;       // [2048][128]
constexpr size_t OFF_K     = OFF_Q + 262144;
constexpr size_t OFF_V     = OFF_K + 262144;
constexpr size_t OFF_AROW  = OFF_V + 262144;         // [2048]
constexpr size_t OFF_AV    = OFF_AROW + 2048;        // [128]
constexpr size_t OFF_FEATS = OFF_AV + 128;           // [1152]
constexpr size_t OFF_F1    = OFF_FEATS + 1152;       // [576]
constexpr size_t OFF_F2    = OFF_F1 + 576;           // [256]
constexpr size_t OFF_GSUM  = OFF_F2 + 256;           // [128]   (memset group start)
constexpr size_t OFF_OUTW  = OFF_GSUM + 128;         // [50000] fp32
constexpr size_t OFF_DEG   = OFF_OUTW + 50000;       // [50000] int (memset group end)
constexpr size_t OFF_ROWP  = OFF_DEG + 50000;        // [50000] int
constexpr size_t OFF_CUR   = OFF_ROWP + 50000;       // [50000] int
constexpr size_t OFF_WPK   = OFF_CUR + 50000;        // [131072] u32 B-frag fp16 w_hh (pre-scaled)
constexpr size_t OFF_EPACK = OFF_WPK + 131072;       // [600000] uint2
constexpr size_t WS_WORDS  = OFF_EPACK + 1200000;

// ---------------- one-time prep: pack w_hh into MFMA B-fragment order.
// (HW-verified by round-7 pass.) u32 index bits:
// jp(0-1) L(2-7) kc(8-9) t(10-12) w(13-14) d(15) layer(16).
// tile t: gate m = t&3, col-group cg = t>>2.
// B[k][n]: n = L&15 -> row = d*512 + m*128 + 32w + 16cg + (L&15)
//          k = (L>>4)*8 + j -> col = kc*32 + (L>>4)*8 + 2jp(+1)
__global__ __launch_bounds__(256) void prep_kernel(
    const float* __restrict__ w_hh0, const float* __restrict__ w_hh1,
    uint32_t* __restrict__ wpk)
{
    int i = blockIdx.x * 256 + threadIdx.x;
    if (i >= 131072) return;
    int jp = i & 3;
    int L  = (i >> 2) & 63;
    int kc = (i >> 8) & 3;
    int t  = (i >> 10) & 7;
    int w  = (i >> 13) & 3;
    int d  = (i >> 15) & 1;
    int layer = i >> 16;
    int m = t & 3, cg = t >> 2;
    const float* W = layer ? w_hh1 : w_hh0;
    int row = d * 512 + m * 128 + 32 * w + 16 * cg + (L & 15);
    int col = kc * 32 + (L >> 4) * 8 + 2 * jp;
    float sc = (m == 2) ? TANH_SCALE : SIG_SCALE;
    _Float16 h2[2];
    h2[0] = (_Float16)(W[(size_t)row * 128 + col] * sc);
    h2[1] = (_Float16)(W[(size_t)row * 128 + col + 1] * sc);
    uint32_t u;
    __builtin_memcpy(&u, h2, 4);
    wpk[i] = u;
}

// ---------------- layer-0 input projection -> xgT[row][t] (biases folded,
// rows pre-scaled by gate constants)
__global__ __launch_bounds__(512) void xg0_kernel(
    const float* __restrict__ g_mol, const float* __restrict__ w_ih,
    const float* __restrict__ b_ih, const float* __restrict__ b_hh,
    float* __restrict__ xgT)
{
    int b = blockIdx.x;
    int dir = b >> 7, t0 = (b & 127) * 16;
    int r = threadIdx.x;
    __shared__ float xs[272];
    if (r < 272) xs[r] = g_mol[t0 * 17 + r];
    __syncthreads();
    const float* wrow = w_ih + (size_t)(dir * 512 + r) * 17;
    float wv[17];
#pragma unroll
    for (int k = 0; k < 17; ++k) wv[k] = wrow[k];
    float bias = b_ih[dir * 512 + r] + b_hh[dir * 512 + r];
    float rs = ((r >> 7) == 2) ? TANH_SCALE : SIG_SCALE;
    float acc[16];
#pragma unroll
    for (int tt = 0; tt < 16; ++tt) {
        float a = bias;
#pragma unroll
        for (int k = 0; k < 17; ++k) a += xs[tt * 17 + k] * wv[k];
        acc[tt] = a * rs;
    }
    float* orow = xgT + (size_t)(dir * 512 + r) * 2048 + t0;
    *(float4*)(orow + 0)  = make_float4(acc[0], acc[1], acc[2], acc[3]);
    *(float4*)(orow + 4)  = make_float4(acc[4], acc[5], acc[6], acc[7]);
    *(float4*)(orow + 8)  = make_float4(acc[8], acc[9], acc[10], acc[11]);
    *(float4*)(orow + 12) = make_float4(acc[12], acc[13], acc[14], acc[15]);
}

// ---------------- layer-1 input projection: hT0 -> xgT[row][t] (pre-scaled)
__global__ __launch_bounds__(512) void xg1_kernel(
    const float* __restrict__ hT0, const float* __restrict__ w_ih,
    const float* __restrict__ b_ih, const float* __restrict__ b_hh,
    float* __restrict__ xgT)
{
    int b = blockIdx.x;
    int dir = b >> 7, t0 = (b & 127) * 16;
    int tid = threadIdx.x;
    __shared__ float xs[16 * 256];            // [tt][k]
    for (int u = tid; u < 1024; u += 512) {
        int k = u >> 2, j4 = u & 3;
        float4 v = *(const float4*)(hT0 + (size_t)k * 2048 + t0 + 4 * j4);
        xs[(4 * j4 + 0) * 256 + k] = v.x;
        xs[(4 * j4 + 1) * 256 + k] = v.y;
        xs[(4 * j4 + 2) * 256 + k] = v.z;
        xs[(4 * j4 + 3) * 256 + k] = v.w;
    }
    __syncthreads();
    int r = tid;
    float bias = b_ih[dir * 512 + r] + b_hh[dir * 512 + r];
    float rs = ((r >> 7) == 2) ? TANH_SCALE : SIG_SCALE;
    float acc[16];
#pragma unroll
    for (int tt = 0; tt < 16; ++tt) acc[tt] = bias;
    const float4* w4 = reinterpret_cast<const float4*>(w_ih + (size_t)(dir * 512 + r) * 256);
    const float4* xs4 = reinterpret_cast<const float4*>(xs);
    for (int k4 = 0; k4 < 64; ++k4) {
        float4 w = w4[k4];
#pragma unroll
        for (int tt = 0; tt < 16; ++tt) {
            float4 x = xs4[tt * 64 + k4];
            acc[tt] += x.x * w.x + x.y * w.y + x.z * w.z + x.w * w.w;
        }
    }
    float* orow = xgT + (size_t)(dir * 512 + r) * 2048 + t0;
    *(float4*)(orow + 0)  = make_float4(acc[0] * rs, acc[1] * rs, acc[2] * rs, acc[3] * rs);
    *(float4*)(orow + 4)  = make_float4(acc[4] * rs, acc[5] * rs, acc[6] * rs, acc[7] * rs);
    *(float4*)(orow + 8)  = make_float4(acc[8] * rs, acc[9] * rs, acc[10] * rs, acc[11] * rs);
    *(float4*)(orow + 12) = make_float4(acc[12] * rs, acc[13] * rs, acc[14] * rs, acc[15] * rs);
}

// ---------------- fused: blocks 0,1 = MFMA LSTM recurrence (one per dir);
// blocks 2..255 = side work (mode 0: edge hist + outw; mode 1: CSR gather).
// 512 thr (8 waves); LSTM uses waves 0-3, waves 4-7 barrier-match during
// steps but help with tile staging. 84KB LDS -> exactly 1 block/CU.
__global__ __launch_bounds__(512) __attribute__((amdgpu_waves_per_eu(2, 2)))
void lstm_fused_kernel(
    const float* __restrict__ xgT, const uint32_t* __restrict__ wpk,
    float* __restrict__ hT, int mode,
    const int* __restrict__ esrc, const int* __restrict__ edst,
    const float* __restrict__ ew,
    int* __restrict__ deg, float* __restrict__ outw,
    const int* __restrict__ rowp, const uint2* __restrict__ epack,
    const float* __restrict__ feat_seq,
    const float* __restrict__ Wgc1, const float* __restrict__ bgc1,
    float* __restrict__ gsum)
{
    __shared__ __align__(16) float smem[21504];   // 84 KB: forces 1 block/CU
    const int tid = threadIdx.x;

    if (blockIdx.x >= 2) {
        if (mode == 0) {
            int stride = (gridDim.x - 2) * 512;
            for (int e = (blockIdx.x - 2) * 512 + tid; e < NEDGE; e += stride) {
                atomicAdd(&deg[edst[e]], 1);
                atomicAdd(&outw[esrc[e]], ew[e]);
            }
        } else {
            // CSR gather: agg1 row -> relu(agg1@W+b) -> gsum += outw[n]*h1
            float* wt   = smem;            // 16384 = W_gc1 [k][o]
            float* bg   = smem + 16384;    // 128
            float* aggl = smem + 16512;    // 8 waves x 128
            float* gbuf = smem + 17536;    // 128
            {
                float4* d4 = (float4*)wt;
                const float4* s4 = (const float4*)Wgc1;
                for (int u = tid; u < 4096; u += 512) d4[u] = s4[u];
                if (tid < 128) { bg[tid] = bgc1[tid]; gbuf[tid] = 0.f; }
            }
            __syncthreads();
            int wv = tid >> 6, lane = tid & 63;
            float ga0 = 0.f, ga1 = 0.f;
            int nwaves = (gridDim.x - 2) * 8;
            for (int n = (blockIdx.x - 2) * 8 + wv; n < NNODE; n += nwaves) {
                int st = rowp[n];
                int dg = deg[n];
                float a0 = 0.f, a1 = 0.f;
                for (int i = 0; i < dg; ++i) {
                    uint2 ep = epack[st + i];
                    float w = __uint_as_float(ep.y);
                    float2 f = *(const float2*)(feat_seq + (size_t)ep.x * 128 + 2 * lane);
                    a0 += w * f.x;
                    a1 += w * f.y;
                }
                *(float2*)&aggl[wv * 128 + 2 * lane] = make_float2(a0, a1);
                float h0 = bg[2 * lane], h1v = bg[2 * lane + 1];
                for (int k = 0; k < 128; ++k) {
                    float av_ = aggl[wv * 128 + k];
                    float2 wv2 = *(const float2*)&wt[k * 128 + 2 * lane];
                    h0 += av_ * wv2.x;
                    h1v += av_ * wv2.y;
                }
                float ow = outw[n];
                ga0 += ow * fmaxf(h0, 0.f);
                ga1 += ow * fmaxf(h1v, 0.f);
            }
            atomicAdd(&gbuf[2 * lane], ga0);
            atomicAdd(&gbuf[2 * lane + 1], ga1);
            __syncthreads();
            if (tid < 128) atomicAdd(&gsum[tid], gbuf[tid]);
        }
        return;
    }

    // ---------------- MFMA LSTM recurrence ----------------
#if __has_builtin(__builtin_amdgcn_s_setprio)
    if (tid < 256) __builtin_amdgcn_s_setprio(3);
#endif
    const int dir = blockIdx.x;
    const int w   = tid >> 6;          // wave 0..7 (0-3 active)
    const int L   = tid & 63;
    const int rg  = L >> 4;            // row-group (M-replicated => redundant)
    const bool hi = (rg & 1);          // tail handles o1 vs o0
    const int o0  = 32 * (w & 3) + (L & 15);
    const int osel = hi ? (o0 + 16) : o0;

    float* xbuf = smem;                                           // [16][512]
    _Float16* hbuf = reinterpret_cast<_Float16*>(smem + 8192);    // [2][128]

    // B-frags: 8 tiles x 4 kc, 16B each, lane-strided (MFMA reads natively)
    half8 bw[8][4];
    if (tid < 256) {
        const half8* wsrc = reinterpret_cast<const half8*>(wpk) + ((size_t)(dir * 4 + w) * 32) * 64;
#pragma unroll
        for (int t = 0; t < 8; ++t)
#pragma unroll
            for (int kc = 0; kc < 4; ++kc)
                bw[t][kc] = wsrc[(t * 4 + kc) * 64 + L];
    }

    if (tid < 128) reinterpret_cast<uint32_t*>(hbuf)[tid] = 0u;  // both buffers
    float c = 0.f;
    float hq[16];
    __syncthreads();

    const float* srow = xgT + (size_t)(dir * 512 + tid) * 2048;  // staging row
    float* hrow = hT + (size_t)(dir * 128 + osel) * 2048;
    const bool dost = (tid < 256) && (L < 32);
    const float4v zro = {0.f, 0.f, 0.f, 0.f};

    for (int s16 = 0; s16 < 128; ++s16) {
        const int base = dir ? (2032 - s16 * 16) : (s16 * 16);

        // ---- stage this tile's xg into LDS (all 512 threads, 1 row each) ----
        {
            float4 A  = *(const float4*)(srow + base);
            float4 B4 = *(const float4*)(srow + base + 4);
            float4 C4 = *(const float4*)(srow + base + 8);
            float4 D4 = *(const float4*)(srow + base + 12);
            xbuf[0 * 512 + tid]  = A.x;  xbuf[1 * 512 + tid]  = A.y;
            xbuf[2 * 512 + tid]  = A.z;  xbuf[3 * 512 + tid]  = A.w;
            xbuf[4 * 512 + tid]  = B4.x; xbuf[5 * 512 + tid]  = B4.y;
            xbuf[6 * 512 + tid]  = B4.z; xbuf[7 * 512 + tid]  = B4.w;
            xbuf[8 * 512 + tid]  = C4.x; xbuf[9 * 512 + tid]  = C4.y;
            xbuf[10 * 512 + tid] = C4.z; xbuf[11 * 512 + tid] = C4.w;
            xbuf[12 * 512 + tid] = D4.x; xbuf[13 * 512 + tid] = D4.y;
            xbuf[14 * 512 + tid] = D4.z; xbuf[15 * 512 + tid] = D4.w;
        }
        __syncthreads();

        if (tid < 256) {
#pragma unroll
            for (int i = 0; i < 16; ++i) {
                const int p = i & 1;
                const int tl = dir ? (15 - i) : i;

                // xq from LDS (<=2-way aliasing, free)
                float xc0 = xbuf[tl * 512 + osel];
                float xc1 = xbuf[tl * 512 + 128 + osel];
                float xc2 = xbuf[tl * 512 + 256 + osel];
                float xc3 = xbuf[tl * 512 + 384 + osel];

                // A-frags: h chunk kc, k = kc*32 + rg*8 + j (matches B pack)
                const char* hbase = reinterpret_cast<const char*>(hbuf) + p * 256 + rg * 16;
                half8 Af[4];
#pragma unroll
                for (int kc = 0; kc < 4; ++kc)
                    Af[kc] = *reinterpret_cast<const half8*>(hbase + kc * 64);

                float4v ac[8];
#pragma unroll
                for (int t = 0; t < 8; ++t)
                    ac[t] = __builtin_amdgcn_mfma_f32_16x16x32_f16(Af[0], bw[t][0], zro, 0, 0, 0);
#pragma unroll
                for (int kc = 1; kc < 4; ++kc)
#pragma unroll
                    for (int t = 0; t < 8; ++t)
                        ac[t] = __builtin_amdgcn_mfma_f32_16x16x32_f16(Af[kc], bw[t][kc], ac[t], 0, 0, 0);

                // rows of D equal (A M-replicated) => .x is the gate sum
                float g0 = (hi ? ac[4].x : ac[0].x) + xc0;   // i
                float g1 = (hi ? ac[5].x : ac[1].x) + xc1;   // f
                float g2 = (hi ? ac[6].x : ac[2].x) + xc2;   // g (tanh)
                float g3 = (hi ? ac[7].x : ac[3].x) + xc3;   // o
                float iv = fast_rcp(1.f + exp2_fast(g0));
                float fv = fast_rcp(1.f + exp2_fast(g1));
                float gv = fmaf(-2.f, fast_rcp(1.f + exp2_fast(g2)), 1.f);
                float ov = fast_rcp(1.f + exp2_fast(g3));
                c = fmaf(fv, c, iv * gv);
                float th = fmaf(-2.f, fast_rcp(1.f + exp2_fast(TANH_SCALE * c)), 1.f);
                float hv = ov * th;

                hbuf[(p ^ 1) * 128 + osel] = (_Float16)hv;   // dup writes same value
                hq[dir ? (15 - i) : i] = hv;
                __syncthreads();
            }
            // batched h store: once per tile (drained at next tile's barrier)
            if (dost) {
                *(float4*)(hrow + base + 0)  = make_float4(hq[0], hq[1], hq[2], hq[3]);
                *(float4*)(hrow + base + 4)  = make_float4(hq[4], hq[5], hq[6], hq[7]);
                *(float4*)(hrow + base + 8)  = make_float4(hq[8], hq[9], hq[10], hq[11]);
                *(float4*)(hrow + base + 12) = make_float4(hq[12], hq[13], hq[14], hq[15]);
            }
        } else {
            // idle waves: match the 16 per-step barriers
            for (int i = 0; i < 16; ++i) __syncthreads();
        }
    }
}

// ---------------- CSR scan: deg -> rowp (exclusive), cursor copy
__global__ __launch_bounds__(1024) void scan_kernel(
    const int* __restrict__ deg, int* __restrict__ rowp, int* __restrict__ cur)
{
    __shared__ int part[1024];
    int t = threadIdx.x;
    int lo = t * 49, hi = min(lo + 49, NNODE);
    int s = 0;
    for (int i = lo; i < hi; ++i) s += deg[i];
    part[t] = s;
    __syncthreads();
    for (int off = 1; off < 1024; off <<= 1) {
        int v = (t >= off) ? part[t - off] : 0;
        __syncthreads();
        part[t] += v;
        __syncthreads();
    }
    int run = t ? part[t - 1] : 0;
    for (int i = lo; i < hi; ++i) {
        rowp[i] = run;
        cur[i] = run;
        run += deg[i];
    }
}

// ---------------- CSR fill: epack[pos] = {src, weight}
__global__ __launch_bounds__(512) void fill_kernel(
    const int* __restrict__ esrc, const int* __restrict__ edst,
    const float* __restrict__ ew, int* __restrict__ cur,
    uint2* __restrict__ epack)
{
    int e = blockIdx.x * 512 + threadIdx.x;
    if (e >= NEDGE) return;
    int d = edst[e];
    int pos = atomicAdd(&cur[d], 1);
    epack[pos] = make_uint2((unsigned)esrc[e], __float_as_uint(ew[e]));
}

// ---------------- q/k/v projection from hT1, 16 timesteps per block
__global__ __launch_bounds__(384) void qkv_kernel(
    const float* __restrict__ hT1,
    const float* __restrict__ Wq, const float* __restrict__ bq,
    const float* __restrict__ Wk, const float* __restrict__ bk,
    const float* __restrict__ Wv, const float* __restrict__ bv,
    float* __restrict__ q, float* __restrict__ k, float* __restrict__ v)
{
    int t0 = blockIdx.x * 16, tid = threadIdx.x;
    __shared__ float xs[16 * 256];
    for (int u = tid; u < 1024; u += 384) {
        int kk = u >> 2, j4 = u & 3;
        float4 vv = *(const float4*)(hT1 + (size_t)kk * 2048 + t0 + 4 * j4);
        xs[(4 * j4 + 0) * 256 + kk] = vv.x;
        xs[(4 * j4 + 1) * 256 + kk] = vv.y;
        xs[(4 * j4 + 2) * 256 + kk] = vv.z;
        xs[(4 * j4 + 3) * 256 + kk] = vv.w;
    }
    __syncthreads();
    int which = tid >> 7, j = tid & 127;
    const float* W = (which == 0) ? Wq : (which == 1) ? Wk : Wv;
    const float* B = (which == 0) ? bq : (which == 1) ? bk : bv;
    float* out = (which == 0) ? q : (which == 1) ? k : v;
    float bias = B[j];
    float acc[16];
#pragma unroll
    for (int tt = 0; tt < 16; ++tt) acc[tt] = bias;
    const float4* w4 = reinterpret_cast<const float4*>(W + (size_t)j * 256);
    const float4* xs4 = reinterpret_cast<const float4*>(xs);
    for (int k4 = 0; k4 < 64; ++k4) {
        float4 w = w4[k4];
#pragma unroll
        for (int tt = 0; tt < 16; ++tt) {
            float4 x = xs4[tt * 64 + k4];
            acc[tt] += x.x * w.x + x.y * w.y + x.z * w.z + x.w * w.w;
        }
    }
#pragma unroll
    for (int tt = 0; tt < 16; ++tt) out[(size_t)(t0 + tt) * 128 + j] = acc[tt];
}

// ---------------- scores = q @ k.T / sqrt(128), straight into d_out+1
__global__ __launch_bounds__(256) void scores_kernel(
    const float* __restrict__ q, const float* __restrict__ kmat, float* __restrict__ attn)
{
    int bi = blockIdx.y, bj = blockIdx.x, tid = threadIdx.x;
    __shared__ float qs[16][132];
    __shared__ float ks[16][132];
    for (int u = tid; u < 2048; u += 256) {
        int rr = u >> 7, cc = u & 127;
        qs[rr][cc] = q[(size_t)(bi * 16 + rr) * 128 + cc];
        ks[rr][cc] = kmat[(size_t)(bj * 16 + rr) * 128 + cc];
    }
    __syncthreads();
    int ty = tid >> 4, tx = tid & 15;
    const float4* qrow = reinterpret_cast<const float4*>(&qs[ty][0]);
    const float4* krow = reinterpret_cast<const float4*>(&ks[tx][0]);
    float acc = 0.f;
#pragma unroll
    for (int c4 = 0; c4 < 32; ++c4) {
        float4 a = qrow[c4], b = krow[c4];
        acc += a.x * b.x + a.y * b.y + a.z * b.z + a.w * b.w;
    }
    attn[(size_t)(bi * 16 + ty) * 2048 + (bj * 16 + tx)] = acc * 0.08838834764831845f;
}

// ---------------- softmax per row, in place; saves row 2047
__global__ __launch_bounds__(256) void softmax_kernel(
    float* __restrict__ attn, float* __restrict__ attnrow)
{
    int i = blockIdx.x, tid = threadIdx.x;
    float* row = attn + (size_t)i * 2048;
    __shared__ float red[256];
    float m = -1e30f;
    for (int j = tid; j < 2048; j += 256) m = fmaxf(m, row[j]);
    red[tid] = m; __syncthreads();
    for (int s = 128; s > 0; s >>= 1) { if (tid < s) red[tid] = fmaxf(red[tid], red[tid + s]); __syncthreads(); }
    m = red[0]; __syncthreads();
    float sum = 0.f;
    for (int j = tid; j < 2048; j += 256) sum += __expf(row[j] - m);
    red[tid] = sum; __syncthreads();
    for (int s = 128; s > 0; s >>= 1) { if (tid < s) red[tid] += red[tid + s]; __syncthreads(); }
    float inv = 1.f / red[0];
    for (int j = tid; j < 2048; j += 256) {
        float w = __expf(row[j] - m) * inv;
        row[j] = w;
        if (i == 2047) attnrow[j] = w;
    }
}

// ---------------- av[j] = sum_t attnrow[t] * v[t][j]
__global__ __launch_bounds__(128) void av_kernel(
    const float* __restrict__ attnrow, const float* __restrict__ v, float* __restrict__ av)
{
    int j = threadIdx.x;
    float acc = 0.f;
#pragma unroll 8
    for (int t = 0; t < 2048; ++t) acc += attnrow[t] * v[(size_t)t * 128 + j];
    av[j] = acc;
}

// ---------------- gmol = av @ Wfc.T + bfc -> feats[256..511]
__global__ __launch_bounds__(256) void gmolfc_kernel(
    const float* __restrict__ av, const float* __restrict__ Wfc, const float* __restrict__ bfc,
    float* __restrict__ feats)
{
    int o = threadIdx.x;
    __shared__ float a[128];
    if (o < 128) a[o] = av[o];
    __syncthreads();
    const float4* w4 = reinterpret_cast<const float4*>(Wfc + (size_t)o * 128);
    const float4* a4 = reinterpret_cast<const float4*>(a);
    float acc = bfc[o];
#pragma unroll 8
    for (int kk = 0; kk < 32; ++kk) {
        float4 w = w4[kk], x = a4[kk];
        acc += x.x * w.x + x.y * w.y + x.z * w.z + x.w * w.w;
    }
    feats[256 + o] = acc;
}

// ---------------- feats: hg (=(gsum/N)@W_gc2+b_gc2) + smiles + kmer
__global__ __launch_bounds__(256) void feats_kernel(
    const float* __restrict__ gsum, const float* __restrict__ W_gc2, const float* __restrict__ b_gc2,
    const float* __restrict__ smiles, const float* __restrict__ kmer, float* __restrict__ feats)
{
    int i = blockIdx.x * 256 + threadIdx.x;
    if (i < 256) {
        float dotv = 0.f;
#pragma unroll 4
        for (int k = 0; k < 128; ++k) dotv += gsum[k] * W_gc2[(size_t)k * 256 + i];
        feats[i] = b_gc2[i] + dotv * (1.f / (float)NNODE);
    } else if (i >= 512 && i < 1086) {
        feats[i] = smiles[i - 512];
    } else if (i >= 1086 && i < 1150) {
        feats[i] = kmer[i - 1086];
    }
}

// ---------------- MLP layers
__global__ __launch_bounds__(256) void mlp1_kernel(
    const float* __restrict__ feats, const float* __restrict__ W1, const float* __restrict__ b1,
    float* __restrict__ f1)
{
    int o = blockIdx.x, tid = threadIdx.x;
    const float* w = W1 + (size_t)o * 1150;
    float acc = 0.f;
    for (int k = tid; k < 1150; k += 256) acc += feats[k] * w[k];
    __shared__ float red[256];
    red[tid] = acc; __syncthreads();
    for (int s = 128; s > 0; s >>= 1) { if (tid < s) red[tid] += red[tid + s]; __syncthreads(); }
    if (tid == 0) f1[o] = fmaxf(red[0] + b1[o], 0.f);
}

__global__ __launch_bounds__(256) void mlp2_kernel(
    const float* __restrict__ f1, const float* __restrict__ W2, const float* __restrict__ b2,
    float* __restrict__ f2)
{
    int o = blockIdx.x, tid = threadIdx.x;
    const float* w = W2 + (size_t)o * 575;
    float acc = 0.f;
    for (int k = tid; k < 575; k += 256) acc += f1[k] * w[k];
    __shared__ float red[256];
    red[tid] = acc; __syncthreads();
    for (int s = 128; s > 0; s >>= 1) { if (tid < s) red[tid] += red[tid + s]; __syncthreads(); }
    if (tid == 0) f2[o] = fmaxf(red[0] + b2[o], 0.f);
}

__global__ __launch_bounds__(256) void mlp_tail_kernel(
    const float* __restrict__ f2,
    const float* __restrict__ W3, const float* __restrict__ b3,
    const float* __restrict__ W4, const float* __restrict__ b4,
    float* __restrict__ out)
{
    __shared__ float f2s[256];
    __shared__ float f3[64];
    int tid = threadIdx.x;
    f2s[tid] = f2[tid];
    __syncthreads();
    if (tid < 64) {
        const float* w = W3 + (size_t)tid * 256;
        float acc = b3[tid];
        for (int k = 0; k < 256; ++k) acc += f2s[k] * w[k];
        f3[tid] = fmaxf(acc, 0.f);
    }
    __syncthreads();
    if (tid == 0) {
        float acc = b4[0];
        for (int k = 0; k < 64; ++k) acc += f3[k] * W4[k];
        out[0] = acc;
    }
}

// ---------------------------------------------------------------------------
extern "C" void kernel_launch(void* const* d_in, const int* in_sizes, int n_in,
                              void* d_out, int out_size, void* d_ws, size_t ws_size,
                              hipStream_t stream)
{
    const float* g_mol   = (const float*)d_in[0];
    const float* feat_seq= (const float*)d_in[1];
    const float* smiles  = (const float*)d_in[2];
    const float* kmer    = (const float*)d_in[3];
    const float* edge_w  = (const float*)d_in[4];
    const float* w_ih0   = (const float*)d_in[5];
    const float* w_hh0   = (const float*)d_in[6];
    const float* b_ih0   = (const float*)d_in[7];
    const float* b_hh0   = (const float*)d_in[8];
    const float* w_ih1   = (const float*)d_in[9];
    const float* w_hh1   = (const float*)d_in[10];
    const float* b_ih1   = (const float*)d_in[11];
    const float* b_hh1   = (const float*)d_in[12];
    const float* Wq      = (const float*)d_in[13];
    const float* bq      = (const float*)d_in[14];
    const float* Wk      = (const float*)d_in[15];
    const float* bk      = (const float*)d_in[16];
    const float* Wv      = (const float*)d_in[17];
    const float* bv      = (const float*)d_in[18];
    const float* Wfc     = (const float*)d_in[19];
    const float* bfc     = (const float*)d_in[20];
    const float* W_gc1   = (const float*)d_in[21];
    const float* b_gc1   = (const float*)d_in[22];
    const float* W_gc2   = (const float*)d_in[23];
    const float* b_gc2   = (const float*)d_in[24];
    const float* W1      = (const float*)d_in[25];
    const float* b1      = (const float*)d_in[26];
    const float* W2      = (const float*)d_in[27];
    const float* b2      = (const float*)d_in[28];
    const float* W3      = (const float*)d_in[29];
    const float* b3      = (const float*)d_in[30];
    const float* W4      = (const float*)d_in[31];
    const float* b4      = (const float*)d_in[32];
    const int* esrc      = (const int*)d_in[33];
    const int* edst      = (const int*)d_in[34];

    float* ws    = (float*)d_ws;
    float* xgT   = ws + OFF_XGT;
    float* hT0   = ws + OFF_HT0;
    float* hT1   = ws + OFF_HT1;
    float* q     = ws + OFF_Q;
    float* k     = ws + OFF_K;
    float* v     = ws + OFF_V;
    float* arow  = ws + OFF_AROW;
    float* av    = ws + OFF_AV;
    float* feats = ws + OFF_FEATS;
    float* f1    = ws + OFF_F1;
    float* f2    = ws + OFF_F2;
    float* gsum  = ws + OFF_GSUM;
    float* outw  = ws + OFF_OUTW;
    int*   deg   = (int*)(ws + OFF_DEG);
    int*   rowp  = (int*)(ws + OFF_ROWP);
    int*   cur   = (int*)(ws + OFF_CUR);
    uint32_t* wpk = (uint32_t*)(ws + OFF_WPK);
    uint2* epack = (uint2*)(ws + OFF_EPACK);

    float* out_f = (float*)d_out;
    float* attn  = out_f + 1;   // [2048][2048] scores then softmax in place

    // zero gsum + outw + deg (contiguous)
    hipMemsetAsync(gsum, 0, (size_t)(128 + 50000 + 50000) * sizeof(float), stream);

    // weight prep + layer-0 input projection
    prep_kernel<<<512, 256, 0, stream>>>(w_hh0, w_hh1, wpk);
    xg0_kernel<<<256, 512, 0, stream>>>(g_mol, w_ih0, b_ih0, b_hh0, xgT);

    // layer-0 recurrence, edge histogram hidden under it (grid=256: 1 block/CU)
    lstm_fused_kernel<<<256, 512, 0, stream>>>(
        xgT, wpk, hT0, 0, esrc, edst, edge_w, deg, outw,
        rowp, epack, feat_seq, W_gc1, b_gc1, gsum);

    // CSR build
    scan_kernel<<<1, 1024, 0, stream>>>(deg, rowp, cur);
    fill_kernel<<<1172, 512, 0, stream>>>(esrc, edst, edge_w, cur, epack);

    // layer-1 input projection, then recurrence with GNN gather hidden under it
    xg1_kernel<<<256, 512, 0, stream>>>(hT0, w_ih1, b_ih1, b_hh1, xgT);
    lstm_fused_kernel<<<256, 512, 0, stream>>>(
        xgT, wpk + 65536, hT1, 1, esrc, edst, edge_w, deg, outw,
        rowp, epack, feat_seq, W_gc1, b_gc1, gsum);

    // attention
    qkv_kernel<<<128, 384, 0, stream>>>(hT1, Wq, bq, Wk, bk, Wv, bv, q, k, v);
    scores_kernel<<<dim3(128, 128), 256, 0, stream>>>(q, k, attn);
    softmax_kernel<<<2048, 256, 0, stream>>>(attn, arow);
    av_kernel<<<1, 128, 0, stream>>>(arow, v, av);
    gmolfc_kernel<<<1, 256, 0, stream>>>(av, Wfc, bfc, feats);
    feats_kernel<<<5, 256, 0, stream>>>(gsum, W_gc2, b_gc2, smiles, kmer, feats);

    // head
    mlp1_kernel<<<575, 256, 0, stream>>>(feats, W1, b1, f1);
    mlp2_kernel<<<256, 256, 0, stream>>>(f1, W2, b2, f2);
    mlp_tail_kernel<<<1, 256, 0, stream>>>(f2, W3, b3, W4, b4, out_f);
}